// Round 12
// baseline (130.227 us; speedup 1.0000x reference)
//
#include <hip/hip_runtime.h>
#include <hip/hip_bf16.h>
#include <math.h>

#define N_STATES 32768
#define N_LABELS 64
#define N_BATCH  512
#define N_CHUNKS 128            // 4 tiles (256 states) per chunk

// ws float layout: Zp[8][128][64] @ ZP_F ; Up[8][64][128][64] @ UP_F (16.8 MB)
// Per-block PRIVATE partials -> plain stores, no atomics, no init; the
// fused->finalize handoff rides a dispatch boundary (the only cross-XCD
// coherence mechanism verified to work here, rounds 8-10).
#define ZP_F     1024
#define UP_F     131072

typedef __attribute__((ext_vector_type(8))) short bfrag;
typedef __attribute__((ext_vector_type(4))) float f32x4;

// pack two fp32 -> two bf16 by TRUNCATION in one v_perm_b32.
// Exact for S in {0,1}; for E it biases U down by ~2^-9 relative (harmless).
#define PSEL 0x07060302u
static __device__ __forceinline__ unsigned pk2(float hi, float lo) {
    return __builtin_amdgcn_perm(__float_as_uint(hi), __float_as_uint(lo), PSEL);
}
static __device__ __forceinline__ unsigned short f2bf(float x) {
    __hip_bfloat16 h = __float2bfloat16(x);     // RNE, used for f only
    return *reinterpret_cast<unsigned short*>(&h);
}

union frag_u { bfrag v; unsigned u[4]; };

// ---------------------------------------------------------------------------
// Fused GEMM1 + exp + GEMM2. Grid 1024 = btile(8) x chunk(128), XCD-affine
// (chunk%8 == blockIdx%8 -> XCD; per-XCD S slice = 16 chunks x 64 KB = 1 MB,
// L2-resident). No LDS in the K-loop; S read straight from global fp32 (0/1
// -> exact bf16 truncation, packed with v_perm). f enters bf16-only (RNE);
// E never leaves registers (GEMM1 C-frag == GEMM2 B-frag, j>=4 zero-padded).
// launch_bounds(256,3) + 33 KB LDS -> 3 blocks/CU (rounds 3-11 ran 2/CU with
// ~200 VGPR live against a 256 budget: latency-exposed and spill-prone; this
// round trades f precision for occupancy).
__global__ __launch_bounds__(256, 3) void fused_kernel(
    const float* __restrict__ f, const float* __restrict__ S,
    float* __restrict__ ws, float* __restrict__ out) {
    __shared__ float mg[4 * 2048];      // 32 KB: two-pass epilogue merge
    __shared__ float zshm[256];         // 1 KB

    const int t     = threadIdx.x;
    const int lane  = t & 63;
    const int w     = t >> 6;
    const int x     = lane & 15;
    const int quad  = lane >> 4;
    const int btile = blockIdx.x >> 7;
    const int chunk = blockIdx.x & 127;

    // ---- f B-frags (bf16 RNE) + M[b] = sum_i max(f,0) via quad butterfly
    //      (upper bound on pot; softmax shift-invariance makes it exact)
    bfrag fh[4][2];
    float Mv[4];
    #pragma unroll
    for (int nt = 0; nt < 4; nt++) {
        const float4* fp = reinterpret_cast<const float4*>(
            f + ((size_t)(btile * 64 + nt * 16 + x)) * N_LABELS);
        float msum = 0.f;
        #pragma unroll
        for (int kh = 0; kh < 2; kh++) {
            float4 a = fp[kh * 8 + quad * 2];
            float4 b = fp[kh * 8 + quad * 2 + 1];
            float vv[8] = {a.x,a.y,a.z,a.w, b.x,b.y,b.z,b.w};
            #pragma unroll
            for (int j = 0; j < 8; j++) {
                msum += fmaxf(vv[j], 0.f);
                fh[nt][kh][j] = (short)f2bf(vv[j]);
            }
        }
        msum += __shfl_xor(msum, 16, 64);
        msum += __shfl_xor(msum, 32, 64);
        Mv[nt] = msum;
    }

    f32x4 Uacc[16];   // [it*4+nt]: U(i=it*16+quad*4+r, b=nt*16+x)
    #pragma unroll
    for (int e = 0; e < 16; e++) Uacc[e] = (f32x4){0.f, 0.f, 0.f, 0.f};
    float zacc[4] = {0.f, 0.f, 0.f, 0.f};

    #pragma unroll
    for (int st = 0; st < 4; st++) {
        const int s0 = (chunk * 4 + st) * 64;

        // ---- GEMM1 A: row s0+16w+x, labels quad*8..+8 and 32+quad*8..+8
        const float* Arow = S + (size_t)(s0 + 16 * w + x) * N_LABELS + quad * 8;
        float4 r0 = *(const float4*)(Arow);
        float4 r1 = *(const float4*)(Arow + 4);
        float4 r2 = *(const float4*)(Arow + 32);
        float4 r3 = *(const float4*)(Arow + 36);
        frag_u a0, a1;
        a0.u[0] = pk2(r0.y, r0.x); a0.u[1] = pk2(r0.w, r0.z);
        a0.u[2] = pk2(r1.y, r1.x); a0.u[3] = pk2(r1.w, r1.z);
        a1.u[0] = pk2(r2.y, r2.x); a1.u[1] = pk2(r2.w, r2.z);
        a1.u[2] = pk2(r3.y, r3.x); a1.u[3] = pk2(r3.w, r3.z);

        // ---- GEMM2 A: S^T[i=16it+x][s=s0+16w+4quad+j], j<4 (high K zeroed)
        const float* Acol = S + (size_t)(s0 + 16 * w + 4 * quad) * N_LABELS + x;
        frag_u A8[4];
        #pragma unroll
        for (int it = 0; it < 4; it++) {
            float c0 = Acol[0 * 64 + it * 16];
            float c1 = Acol[1 * 64 + it * 16];
            float c2 = Acol[2 * 64 + it * 16];
            float c3 = Acol[3 * 64 + it * 16];
            A8[it].u[0] = pk2(c1, c0);
            A8[it].u[1] = pk2(c3, c2);
            A8[it].u[2] = 0; A8[it].u[3] = 0;
        }

        #pragma unroll
        for (int nt = 0; nt < 4; nt++) {
            f32x4 acc = (f32x4){0.f, 0.f, 0.f, 0.f};
            acc = __builtin_amdgcn_mfma_f32_16x16x32_bf16(a0.v, fh[nt][0], acc, 0, 0, 0);
            acc = __builtin_amdgcn_mfma_f32_16x16x32_bf16(a1.v, fh[nt][1], acc, 0, 0, 0);
            float e0 = __expf(acc[0] - Mv[nt]);
            float e1 = __expf(acc[1] - Mv[nt]);
            float e2 = __expf(acc[2] - Mv[nt]);
            float e3 = __expf(acc[3] - Mv[nt]);
            zacc[nt] += (e0 + e1) + (e2 + e3);
            // E in-register as GEMM2 B-frag (k=8q+j -> s=16w+4q+j, j<4)
            frag_u Bf;
            Bf.u[0] = pk2(e1, e0);
            Bf.u[1] = pk2(e3, e2);
            Bf.u[2] = 0; Bf.u[3] = 0;
            #pragma unroll
            for (int it = 0; it < 4; it++)
                Uacc[it * 4 + nt] =
                    __builtin_amdgcn_mfma_f32_16x16x32_bf16(A8[it].v, Bf.v, Uacc[it * 4 + nt], 0, 0, 0);
        }
    }

    // ---- Z partials (pass 0 does the LDS work alongside)
    #pragma unroll
    for (int nt = 0; nt < 4; nt++) {
        float v = zacc[nt];
        v += __shfl_down(v, 32, 64);
        v += __shfl_down(v, 16, 64);
        if (quad == 0) zshm[w * 64 + nt * 16 + x] = v;
    }

    // ---- two-pass merge of the 4 wave partials (32 KB LDS)
    float* Up = ws + UP_F;
    #pragma unroll
    for (int pass = 0; pass < 2; pass++) {
        if (pass) __syncthreads();          // pass-0 reads done before overwrite
        #pragma unroll
        for (int el = 0; el < 8; el++) {
            int e = pass * 8 + el;
            #pragma unroll
            for (int r = 0; r < 4; r++)
                mg[w * 2048 + (el * 4 + r) * 64 + lane] = Uacc[e][r];
        }
        __syncthreads();
        #pragma unroll
        for (int k = 0; k < 8; k++) {
            int idx  = k * 256 + t;         // 0..2047
            int slot = idx >> 6;            // el*4 + r
            int ln   = idx & 63;
            int el   = slot >> 2, r = slot & 3;
            int it   = pass * 2 + (el >> 2);
            int nt   = el & 3;
            int i    = it * 16 + (ln >> 4) * 4 + r;
            int b    = nt * 16 + (ln & 15);
            float s = mg[idx] + mg[2048 + idx] + mg[4096 + idx] + mg[6144 + idx];
            Up[((size_t)(btile * 64 + i) * N_CHUNKS + chunk) * 64 + b] = s;
        }
    }
    if (t < 64) {
        float z = zshm[t] + zshm[64 + t] + zshm[128 + t] + zshm[192 + t];
        (ws + ZP_F)[(btile * N_CHUNKS + chunk) * 64 + t] = z;
    }
    if (blockIdx.x == 0 && t == 0) out[0] = 0.f;   // before finalize dispatch
}

// ---------------------------------------------------------------------------
// Finalize (separate dispatch = coherence boundary): sum 128 chunk partials,
// p = U/Z, clamp, write out[1..]; masked BCE (log clamp -100), block reduce,
// atomicAdd loss into out[0].
__global__ __launch_bounds__(256) void finalize_kernel(
    const float* __restrict__ ws, const float* __restrict__ y,
    const float* __restrict__ mask, float* __restrict__ out) {
    const int i     = blockIdx.x >> 1;
    const int b     = ((blockIdx.x & 1) << 8) + threadIdx.x;
    const int btile = b >> 6;
    const int bl    = b & 63;

    const float* zp = ws + ZP_F + (size_t)(btile * N_CHUNKS) * 64 + bl;
    const float* up = ws + UP_F + ((size_t)(btile * 64 + i) * N_CHUNKS) * 64 + bl;
    float z = 0.f, u = 0.f;
    #pragma unroll 8
    for (int c = 0; c < N_CHUNKS; c++) { z += zp[c * 64]; u += up[c * 64]; }

    float p = fminf(fmaxf(u / z, 0.f), 1.f);
    const int idx = b * 64 + i;
    out[1 + idx] = p;

    float lp  = fmaxf(logf(p), -100.f);
    float l1p = fmaxf(logf(1.f - p), -100.f);
    float yy = y[idx];
    float bce = -(yy * lp + (1.f - yy) * l1p) * mask[idx] * (1.f / (float)N_BATCH);

    float v = bce;
    #pragma unroll
    for (int off = 32; off > 0; off >>= 1) v += __shfl_down(v, off, 64);
    __shared__ float wsum[4];
    if ((threadIdx.x & 63) == 0) wsum[threadIdx.x >> 6] = v;
    __syncthreads();
    if (threadIdx.x == 0)
        atomicAdd(&out[0], wsum[0] + wsum[1] + wsum[2] + wsum[3]);
}

// ---------------------------------------------------------------------------
extern "C" void kernel_launch(void* const* d_in, const int* in_sizes, int n_in,
                              void* d_out, int out_size, void* d_ws, size_t ws_size,
                              hipStream_t stream) {
    const float* f    = (const float*)d_in[0];   // [512, 64]
    const float* S    = (const float*)d_in[1];   // [32768, 64]
    const float* y    = (const float*)d_in[2];   // [512, 64]
    const float* mask = (const float*)d_in[3];   // [512, 64]
    float* out = (float*)d_out;                  // [1 + 512*64]
    float* ws  = (float*)d_ws;

    fused_kernel<<<1024, 256, 0, stream>>>(f, S, ws, out);
    finalize_kernel<<<128, 256, 0, stream>>>(ws, y, mask, out);
}